// Round 7
// baseline (13187.904 us; speedup 1.0000x reference)
//
#include <hip/hip_runtime.h>
#include <stdint.h>

#define T_STEPS 1024
#define BATCH   64
#define DIN     256
#define HDIM    512
#define G4      2048
#define NGRP    8        // groups = XCDs
#define GWG     32       // WGs per group
#define GB      8        // batches per group
#define NBUF    16       // h ring depth (defeats L1 reuse; WGs stay within 1 step)

// ---- workspace layout (bytes) ----
#define OFF_XCNT  0                            // 8 ints: per-XCD rank counters
#define OFF_ARR   1024                         // [8 groups][8 lines x 128B] arrive counters
#define OFF_BIAS  20480                        // 2048 f32 (b_ih + b_hh)
#define OFF_WHH   32768                        // 2048*512 bf16 (2 MB)
#define OFF_WIH   (OFF_WHH + G4*HDIM*2)        // 2048*256 bf16 (1 MB)
#define OFF_H     (OFF_WIH + G4*DIN*2)         // [NGRP][NBUF][8][512] bf16 = 1 MB
// total ≈ 4.2 MB

typedef __attribute__((ext_vector_type(8))) short bf16x8;
typedef __attribute__((ext_vector_type(4))) float f32x4;

__device__ __forceinline__ unsigned short f2bf(float f) {
  union { float f; unsigned u; } v; v.f = f;
  unsigned r = v.u + 0x7FFF + ((v.u >> 16) & 1);
  return (unsigned short)(r >> 16);
}
__device__ __forceinline__ float sigm(float x)   { return 1.0f / (1.0f + __expf(-x)); }
__device__ __forceinline__ float tanh_f(float x) { return 2.0f / (1.0f + __expf(-2.0f * x)) - 1.0f; }

__global__ void k_init(unsigned char* ws) {
  int tid = blockIdx.x * blockDim.x + threadIdx.x;
  unsigned* w32 = (unsigned*)ws;
  for (int i = tid; i < 20480 / 4; i += gridDim.x * blockDim.x) w32[i] = 0;
}

__global__ void k_pack(const float* __restrict__ W_ih, const float* __restrict__ W_hh,
                       const float* __restrict__ b_ih, const float* __restrict__ b_hh,
                       unsigned char* ws) {
  unsigned short* whh = (unsigned short*)(ws + OFF_WHH);
  unsigned short* wih = (unsigned short*)(ws + OFF_WIH);
  float* bias = (float*)(ws + OFF_BIAS);
  int tid = blockIdx.x * blockDim.x + threadIdx.x;
  int np = gridDim.x * blockDim.x;
  for (int i = tid; i < G4 * HDIM; i += np) whh[i] = f2bf(W_hh[i]);
  for (int i = tid; i < G4 * DIN;  i += np) wih[i] = f2bf(W_ih[i]);
  for (int i = tid; i < G4;        i += np) bias[i] = b_ih[i] + b_hh[i];
}

// stage x[t] for this group's 8 batches into A_s x-region (bf16), direct from fp32 input
__device__ __forceinline__ void stage_x(const float* __restrict__ x, unsigned short* A_s,
                                        int g, int m, int c, int tstep) {
  const float* xb = x + ((size_t)(g * GB + m) * 1024 + tstep) * 256 + c * 8;
  float4 f0 = *(const float4*)(xb);
  float4 f1 = *(const float4*)(xb + 4);
  union { bf16x8 v; unsigned short s[8]; } u;
  u.s[0] = f2bf(f0.x); u.s[1] = f2bf(f0.y); u.s[2] = f2bf(f0.z); u.s[3] = f2bf(f0.w);
  u.s[4] = f2bf(f1.x); u.s[5] = f2bf(f1.y); u.s[6] = f2bf(f1.z); u.s[7] = f2bf(f1.w);
  *(bf16x8*)(A_s + m * 776 + 512 + c * 8) = u.v;
}

// 512 WGs x 256 thr launched; 32 participants per XCD (group = physical XCD).
// WG covers 8 batches x 64 gate cols (4 gates x 16 j), K=768. Exchange is XCD-L2-local.
__global__ __launch_bounds__(256, 1) void k_lstm(unsigned char* ws,
                                                 const float* __restrict__ x,
                                                 float* __restrict__ out) {
  __shared__ __attribute__((aligned(16))) unsigned short A_s[16 * 776];   // [16][512h|256x|8pad]
  __shared__ __attribute__((aligned(16))) unsigned short Whh_s[64 * 520]; // [64 cols][512+8]
  __shared__ __attribute__((aligned(16))) unsigned short Wih_s[64 * 264]; // [64 cols][256+8]
  __shared__ __attribute__((aligned(16))) float gl[16 * 64];
  __shared__ int s_rank;

  const int tid = threadIdx.x;

  unsigned xcc;
  asm("s_getreg_b32 %0, hwreg(HW_REG_XCC_ID)" : "=s"(xcc));
  xcc &= 7;
  unsigned* xcnt = (unsigned*)(ws + OFF_XCNT);
  if (tid == 0)
    s_rank = (int)__hip_atomic_fetch_add(&xcnt[xcc], 1u, __ATOMIC_RELAXED, __HIP_MEMORY_SCOPE_AGENT);
  __syncthreads();
  const int rank = s_rank;
  if (rank >= GWG) return;                    // non-participant exits, frees CU

  const int g  = (int)xcc;
  const int jt = rank;                        // j-tile 0..31 (16 j each)

  const unsigned short* whh_g = (const unsigned short*)(ws + OFF_WHH);
  const unsigned short* wih_g = (const unsigned short*)(ws + OFF_WIH);
  const float*          bias_g = (const float*)(ws + OFF_BIAS);
  unsigned short*       hring = (unsigned short*)(ws + OFF_H) + (size_t)g * (NBUF * GB * HDIM);
  unsigned*             arr   = (unsigned*)(ws + OFF_ARR + g * 2048);   // 8 lines, 32 dw apart

  // --- preload W slices: LDS row rl (0..63) = gate col; gate=rl>>4, jloc=rl&15 ---
  {
    int rl = tid >> 2, part = tid & 3;
    int grow = (rl >> 4) * 512 + jt * 16 + (rl & 15);
    const unsigned short* src = whh_g + grow * 512 + part * 128;
    unsigned short* dst = Whh_s + rl * 520 + part * 128;
    #pragma unroll
    for (int i = 0; i < 16; ++i) *(bf16x8*)(dst + i * 8) = *(const bf16x8*)(src + i * 8);
    const unsigned short* src2 = wih_g + grow * 256 + part * 64;
    unsigned short* dst2 = Wih_s + rl * 264 + part * 64;
    #pragma unroll
    for (int i = 0; i < 8; ++i) *(bf16x8*)(dst2 + i * 8) = *(const bf16x8*)(src2 + i * 8);
  }

  // --- zero A_s (h(0)=0; pad rows 8..15 stay zero forever) ---
  {
    unsigned* a32 = (unsigned*)A_s;
    for (int i = tid; i < 16 * 776 / 2; i += 256) a32[i] = 0;
  }

  float biasr[4];
  float c_reg = 0.f;
  const int ub = tid >> 4, jl = tid & 15;     // updater mapping (tid<128)
  if (tid < 128) {
    #pragma unroll
    for (int gt = 0; gt < 4; ++gt)
      biasr[gt] = bias_g[gt * 512 + jt * 16 + jl];
  }

  const int lane = tid & 63, wave = tid >> 6;  // wave = gate (i,f,g,o)
  const int arow = lane & 15;
  const int kg   = (lane >> 4) * 8;
  const int rl   = wave * 16 + (lane & 15);    // B row (gate col within WG)
  const int sm   = tid >> 5, sc = tid & 31;    // staging mapping: 8 rows x 32 thr
  const int aline = (rank * 2 + wave) & 7;     // arrive line for this wave (waves 0,1)

  __syncthreads();

  // --- preamble: stage x(0); accX(0); stage x(1) ---
  stage_x(x, A_s, g, sm, sc, 0);
  __syncthreads();
  f32x4 accX;
  {
    f32x4 xa = {0.f,0.f,0.f,0.f}, xb2 = {0.f,0.f,0.f,0.f};
    #pragma unroll
    for (int kx = 0; kx < 4; ++kx) {
      bf16x8 a = *(const bf16x8*)(A_s + arow * 776 + 512 + kx * 32 + kg);
      bf16x8 b = *(const bf16x8*)(Wih_s + rl * 264 + kx * 32 + kg);
      xa = __builtin_amdgcn_mfma_f32_16x16x32_bf16(a, b, xa, 0, 0, 0);
    }
    #pragma unroll
    for (int kx = 4; kx < 8; ++kx) {
      bf16x8 a = *(const bf16x8*)(A_s + arow * 776 + 512 + kx * 32 + kg);
      bf16x8 b = *(const bf16x8*)(Wih_s + rl * 264 + kx * 32 + kg);
      xb2 = __builtin_amdgcn_mfma_f32_16x16x32_bf16(a, b, xb2, 0, 0, 0);
    }
    #pragma unroll
    for (int r = 0; r < 4; ++r) accX[r] = xa[r] + xb2[r];
  }
  __syncthreads();
  stage_x(x, A_s, g, sm, sc, 1);
  __syncthreads();

  // --- main loop. Top of iter t: A_s-h = h(t), A_s-x = x(t+1), accX = xproj(t). ---
  for (int t = 0; t < T_STEPS; ++t) {
    // h-part MFMAs: 2 independent chains of 8
    f32x4 acc0 = accX, acc1 = {0.f,0.f,0.f,0.f};
    #pragma unroll
    for (int kk = 0; kk < 8; ++kk) {
      bf16x8 a = *(const bf16x8*)(A_s + arow * 776 + kk * 32 + kg);
      bf16x8 b = *(const bf16x8*)(Whh_s + rl * 520 + kk * 32 + kg);
      acc0 = __builtin_amdgcn_mfma_f32_16x16x32_bf16(a, b, acc0, 0, 0, 0);
    }
    #pragma unroll
    for (int kk = 8; kk < 16; ++kk) {
      bf16x8 a = *(const bf16x8*)(A_s + arow * 776 + kk * 32 + kg);
      bf16x8 b = *(const bf16x8*)(Whh_s + rl * 520 + kk * 32 + kg);
      acc1 = __builtin_amdgcn_mfma_f32_16x16x32_bf16(a, b, acc1, 0, 0, 0);
    }
    #pragma unroll
    for (int r = 0; r < 4; ++r) {
      int m = (lane >> 4) * 4 + r;             // C/D: row=(lane>>4)*4+reg, col=lane&15
      gl[m * 64 + wave * 16 + (lane & 15)] = acc0[r] + acc1[r];
    }
    __syncthreads();                           // S1: gates visible

    // update (tid<128): gates -> c,h; h store; per-wave vmcnt drain + arrive
    float hv = 0.f;
    if (tid < 128) {
      float gi = gl[ub * 64 +      jl] + biasr[0];
      float gf = gl[ub * 64 + 16 + jl] + biasr[1];
      float gg = gl[ub * 64 + 32 + jl] + biasr[2];
      float go = gl[ub * 64 + 48 + jl] + biasr[3];
      float cv = sigm(gf) * c_reg + sigm(gi) * tanh_f(gg);
      c_reg = cv;
      hv = sigm(go) * tanh_f(cv);
      if (t + 1 < T_STEPS) {
        unsigned short* hd = hring + (size_t)((t + 1) & (NBUF - 1)) * (GB * HDIM);
        hd[ub * HDIM + jt * 16 + jl] = f2bf(hv);
        asm volatile("s_waitcnt vmcnt(0)" ::: "memory");   // this wave's h half at L2
        if (lane == 0)                                      // per-wave arrival (2 per WG)
          __hip_atomic_fetch_add(&arr[aline * 32], 1u,
                                 __ATOMIC_RELAXED, __HIP_MEMORY_SCOPE_WORKGROUP);
      }
      out[((size_t)t * 64 + g * GB + ub) * 512 + jt * 16 + jl] = sigm(hv);
    }

    if (t + 1 < T_STEPS) {
      // overlap: x(t+1) projection while group finishes (2 chains of 4)
      {
        f32x4 xa = {0.f,0.f,0.f,0.f}, xb2 = {0.f,0.f,0.f,0.f};
        #pragma unroll
        for (int kx = 0; kx < 4; ++kx) {
          bf16x8 a = *(const bf16x8*)(A_s + arow * 776 + 512 + kx * 32 + kg);
          bf16x8 b = *(const bf16x8*)(Wih_s + rl * 264 + kx * 32 + kg);
          xa = __builtin_amdgcn_mfma_f32_16x16x32_bf16(a, b, xa, 0, 0, 0);
        }
        #pragma unroll
        for (int kx = 4; kx < 8; ++kx) {
          bf16x8 a = *(const bf16x8*)(A_s + arow * 776 + 512 + kx * 32 + kg);
          bf16x8 b = *(const bf16x8*)(Wih_s + rl * 264 + kx * 32 + kg);
          xb2 = __builtin_amdgcn_mfma_f32_16x16x32_bf16(a, b, xb2, 0, 0, 0);
        }
        #pragma unroll
        for (int r = 0; r < 4; ++r) accX[r] = xa[r] + xb2[r];
      }
      // poll (tid==0): fast sc0 read-burst (L1-bypass, L2-serve, non-serializing);
      // after 64 tries, fall back to RMW poll (stale-proof) and LOOP UNTIL satisfied.
      if (tid == 0) {
        const unsigned target = 8u * (unsigned)(t + 1);
        int it = 0;
        for (;;) {
          unsigned a0,a1,a2,a3,a4,a5,a6,a7;
          asm volatile(
            "global_load_dword %0, %[p], off sc0\n\t"
            "global_load_dword %1, %[p], off offset:128 sc0\n\t"
            "global_load_dword %2, %[p], off offset:256 sc0\n\t"
            "global_load_dword %3, %[p], off offset:384 sc0\n\t"
            "global_load_dword %4, %[p], off offset:512 sc0\n\t"
            "global_load_dword %5, %[p], off offset:640 sc0\n\t"
            "global_load_dword %6, %[p], off offset:768 sc0\n\t"
            "global_load_dword %7, %[p], off offset:896 sc0\n\t"
            "s_waitcnt vmcnt(0)"
            : "=&v"(a0), "=&v"(a1), "=&v"(a2), "=&v"(a3),
              "=&v"(a4), "=&v"(a5), "=&v"(a6), "=&v"(a7)
            : [p]"v"(arr)
            : "memory");
          unsigned mn = a0 & 0x7FFFFFFFu;
          mn = mn < (a1 & 0x7FFFFFFFu) ? mn : (a1 & 0x7FFFFFFFu);
          mn = mn < (a2 & 0x7FFFFFFFu) ? mn : (a2 & 0x7FFFFFFFu);
          mn = mn < (a3 & 0x7FFFFFFFu) ? mn : (a3 & 0x7FFFFFFFu);
          mn = mn < (a4 & 0x7FFFFFFFu) ? mn : (a4 & 0x7FFFFFFFu);
          mn = mn < (a5 & 0x7FFFFFFFu) ? mn : (a5 & 0x7FFFFFFFu);
          mn = mn < (a6 & 0x7FFFFFFFu) ? mn : (a6 & 0x7FFFFFFFu);
          mn = mn < (a7 & 0x7FFFFFFFu) ? mn : (a7 & 0x7FFFFFFFu);
          if (mn >= target) break;
          if (++it > 64) {                     // verified fallback: RMW (always L2-fresh)
            bool ok = true;
            #pragma unroll
            for (int l = 0; l < 8; ++l) {
              unsigned v = __hip_atomic_fetch_or(&arr[l * 32], 0x80000000u,
                                                 __ATOMIC_RELAXED, __HIP_MEMORY_SCOPE_WORKGROUP);
              if ((v & 0x7FFFFFFFu) < target) ok = false;
            }
            if (ok) break;
            it = 0;
            __builtin_amdgcn_s_sleep(2);
          }
        }
      }
      __syncthreads();                         // S3: h(t+1) ready group-wide
      // stage h(t+1) from ring (fresh ring addresses -> plain loads safe) + x(t+2)
      {
        const unsigned short* hs = hring + (size_t)((t + 1) & (NBUF - 1)) * (GB * HDIM)
                                 + sm * HDIM + sc * 16;
        bf16x8 h0 = *(const bf16x8*)(hs);
        bf16x8 h1 = *(const bf16x8*)(hs + 8);
        *(bf16x8*)(A_s + sm * 776 + sc * 16)     = h0;
        *(bf16x8*)(A_s + sm * 776 + sc * 16 + 8) = h1;
        if (t + 2 < T_STEPS) stage_x(x, A_s, g, sm, sc, t + 2);
      }
      __syncthreads();                         // S4: A_s consistent for next iter
    }
  }
}

extern "C" void kernel_launch(void* const* d_in, const int* in_sizes, int n_in,
                              void* d_out, int out_size, void* d_ws, size_t ws_size,
                              hipStream_t stream) {
  const float* x    = (const float*)d_in[0];
  const float* W_ih = (const float*)d_in[1];
  const float* W_hh = (const float*)d_in[2];
  const float* b_ih = (const float*)d_in[3];
  const float* b_hh = (const float*)d_in[4];
  float* out = (float*)d_out;
  unsigned char* ws = (unsigned char*)d_ws;

  hipLaunchKernelGGL(k_init, dim3(8),    dim3(256), 0, stream, ws);
  hipLaunchKernelGGL(k_pack, dim3(1024), dim3(256), 0, stream, W_ih, W_hh, b_ih, b_hh, ws);
  hipLaunchKernelGGL(k_lstm, dim3(512),  dim3(256), 0, stream, ws, x, out);
}

// Round 8
// 3704.271 us; speedup vs baseline: 3.5602x; 3.5602x over previous
//
#include <hip/hip_runtime.h>
#include <stdint.h>

#define T_STEPS 1024
#define BATCH   64
#define DIN     256
#define HDIM    512
#define G4      2048
#define NGRP    8        // groups = XCDs
#define GWG     32       // WGs per group
#define GB      8        // batches per group
#define NBUF    16       // h ring depth (defeats L1 reuse; WGs stay within 1 step)

// ---- workspace layout (bytes) ----
// Sync region per group (8 KB): 128B lines: [0..7]=arrive, [8]=level2, [9..40]=GO per rank
#define OFF_XCNT  0                            // 8 ints: per-XCD rank counters
#define OFF_ARR   4096                         // [8 groups][8192 B]
#define OFF_BIAS  (4096 + NGRP*8192)           // 2048 f32 (b_ih + b_hh)
#define OFF_WHH   (OFF_BIAS + 8192)            // 2048*512 bf16 (2 MB)
#define OFF_WIH   (OFF_WHH + G4*HDIM*2)        // 2048*256 bf16 (1 MB)
#define OFF_H     (OFF_WIH + G4*DIN*2)         // [NGRP][NBUF][8][512] bf16 = 1 MB

typedef __attribute__((ext_vector_type(8))) short bf16x8;
typedef __attribute__((ext_vector_type(4))) float f32x4;

__device__ __forceinline__ unsigned short f2bf(float f) {
  union { float f; unsigned u; } v; v.f = f;
  unsigned r = v.u + 0x7FFF + ((v.u >> 16) & 1);
  return (unsigned short)(r >> 16);
}
__device__ __forceinline__ float sigm(float x)   { return 1.0f / (1.0f + __expf(-x)); }
__device__ __forceinline__ float tanh_f(float x) { return 2.0f / (1.0f + __expf(-2.0f * x)) - 1.0f; }

__global__ void k_init(unsigned char* ws) {
  int tid = blockIdx.x * blockDim.x + threadIdx.x;
  unsigned* w32 = (unsigned*)ws;
  for (int i = tid; i < (int)(OFF_BIAS / 4); i += gridDim.x * blockDim.x) w32[i] = 0;
}

__global__ void k_pack(const float* __restrict__ W_ih, const float* __restrict__ W_hh,
                       const float* __restrict__ b_ih, const float* __restrict__ b_hh,
                       unsigned char* ws) {
  unsigned short* whh = (unsigned short*)(ws + OFF_WHH);
  unsigned short* wih = (unsigned short*)(ws + OFF_WIH);
  float* bias = (float*)(ws + OFF_BIAS);
  int tid = blockIdx.x * blockDim.x + threadIdx.x;
  int np = gridDim.x * blockDim.x;
  for (int i = tid; i < G4 * HDIM; i += np) whh[i] = f2bf(W_hh[i]);
  for (int i = tid; i < G4 * DIN;  i += np) wih[i] = f2bf(W_ih[i]);
  for (int i = tid; i < G4;        i += np) bias[i] = b_ih[i] + b_hh[i];
}

// stage x[t] for this group's 8 batches into A_s x-region (bf16), direct from fp32 input
__device__ __forceinline__ void stage_x(const float* __restrict__ x, unsigned short* A_s,
                                        int g, int m, int c, int tstep) {
  const float* xb = x + ((size_t)(g * GB + m) * 1024 + tstep) * 256 + c * 8;
  float4 f0 = *(const float4*)(xb);
  float4 f1 = *(const float4*)(xb + 4);
  union { bf16x8 v; unsigned short s[8]; } u;
  u.s[0] = f2bf(f0.x); u.s[1] = f2bf(f0.y); u.s[2] = f2bf(f0.z); u.s[3] = f2bf(f0.w);
  u.s[4] = f2bf(f1.x); u.s[5] = f2bf(f1.y); u.s[6] = f2bf(f1.z); u.s[7] = f2bf(f1.w);
  *(bf16x8*)(A_s + m * 776 + 512 + c * 8) = u.v;
}

// 512 WGs x 256 thr launched; 32 participants per XCD (group = physical XCD).
// WG covers 8 batches x 64 gate cols (4 gates x 16 j), K=768. Exchange is XCD-L2-local.
// Sync: RMW-only (loads through L1 are stale-prone on gfx950 — r6/r7 evidence).
__global__ __launch_bounds__(256, 1) void k_lstm(unsigned char* ws,
                                                 const float* __restrict__ x,
                                                 float* __restrict__ out) {
  __shared__ __attribute__((aligned(16))) unsigned short A_s[16 * 776];   // [16][512h|256x|8pad]
  __shared__ __attribute__((aligned(16))) unsigned short Whh_s[64 * 520]; // [64 cols][512+8]
  __shared__ __attribute__((aligned(16))) unsigned short Wih_s[64 * 264]; // [64 cols][256+8]
  __shared__ __attribute__((aligned(16))) float gl[16 * 64];
  __shared__ int s_rank;

  const int tid = threadIdx.x;

  unsigned xcc;
  asm("s_getreg_b32 %0, hwreg(HW_REG_XCC_ID)" : "=s"(xcc));
  xcc &= 7;
  unsigned* xcnt = (unsigned*)(ws + OFF_XCNT);
  if (tid == 0)
    s_rank = (int)__hip_atomic_fetch_add(&xcnt[xcc], 1u, __ATOMIC_RELAXED, __HIP_MEMORY_SCOPE_AGENT);
  __syncthreads();
  const int rank = s_rank;
  if (rank >= GWG) return;                    // non-participant exits, frees CU

  const int g  = (int)xcc;
  const int jt = rank;                        // j-tile 0..31 (16 j each)

  const unsigned short* whh_g = (const unsigned short*)(ws + OFF_WHH);
  const unsigned short* wih_g = (const unsigned short*)(ws + OFF_WIH);
  const float*          bias_g = (const float*)(ws + OFF_BIAS);
  unsigned short*       hring = (unsigned short*)(ws + OFF_H) + (size_t)g * (NBUF * GB * HDIM);
  unsigned*             arr   = (unsigned*)(ws + OFF_ARR + g * 8192);  // 128B lines, 32 dw apart

  // --- preload W slices: LDS row rl (0..63) = gate col; gate=rl>>4, jloc=rl&15 ---
  {
    int rl = tid >> 2, part = tid & 3;
    int grow = (rl >> 4) * 512 + jt * 16 + (rl & 15);
    const unsigned short* src = whh_g + grow * 512 + part * 128;
    unsigned short* dst = Whh_s + rl * 520 + part * 128;
    #pragma unroll
    for (int i = 0; i < 16; ++i) *(bf16x8*)(dst + i * 8) = *(const bf16x8*)(src + i * 8);
    const unsigned short* src2 = wih_g + grow * 256 + part * 64;
    unsigned short* dst2 = Wih_s + rl * 264 + part * 64;
    #pragma unroll
    for (int i = 0; i < 8; ++i) *(bf16x8*)(dst2 + i * 8) = *(const bf16x8*)(src2 + i * 8);
  }

  // --- zero A_s (h(0)=0; pad rows 8..15 stay zero forever) ---
  {
    unsigned* a32 = (unsigned*)A_s;
    for (int i = tid; i < 16 * 776 / 2; i += 256) a32[i] = 0;
  }

  float biasr[4];
  float c_reg = 0.f;
  const int ub = tid >> 4, jl = tid & 15;     // updater mapping (tid<128)
  if (tid < 128) {
    #pragma unroll
    for (int gt = 0; gt < 4; ++gt)
      biasr[gt] = bias_g[gt * 512 + jt * 16 + jl];
  }

  const int lane = tid & 63, wave = tid >> 6;  // wave = gate (i,f,g,o)
  const int arow = lane & 15;
  const int kg   = (lane >> 4) * 8;
  const int rl   = wave * 16 + (lane & 15);    // B row (gate col within WG)
  const int sm   = tid >> 5, sc = tid & 31;    // staging mapping: 8 rows x 32 thr
  const int aline = (rank * 2 + wave) & 7;     // arrive line for this wave (waves 0,1)

  __syncthreads();

  // --- preamble: stage x(0); accX(0); stage x(1) ---
  stage_x(x, A_s, g, sm, sc, 0);
  __syncthreads();
  f32x4 accX;
  {
    f32x4 xa = {0.f,0.f,0.f,0.f}, xb2 = {0.f,0.f,0.f,0.f};
    #pragma unroll
    for (int kx = 0; kx < 4; ++kx) {
      bf16x8 a = *(const bf16x8*)(A_s + arow * 776 + 512 + kx * 32 + kg);
      bf16x8 b = *(const bf16x8*)(Wih_s + rl * 264 + kx * 32 + kg);
      xa = __builtin_amdgcn_mfma_f32_16x16x32_bf16(a, b, xa, 0, 0, 0);
    }
    #pragma unroll
    for (int kx = 4; kx < 8; ++kx) {
      bf16x8 a = *(const bf16x8*)(A_s + arow * 776 + 512 + kx * 32 + kg);
      bf16x8 b = *(const bf16x8*)(Wih_s + rl * 264 + kx * 32 + kg);
      xb2 = __builtin_amdgcn_mfma_f32_16x16x32_bf16(a, b, xb2, 0, 0, 0);
    }
    #pragma unroll
    for (int r = 0; r < 4; ++r) accX[r] = xa[r] + xb2[r];
  }
  __syncthreads();
  stage_x(x, A_s, g, sm, sc, 1);
  __syncthreads();

  // --- main loop. Top of iter t: A_s-h = h(t), A_s-x = x(t+1), accX = xproj(t). ---
  for (int t = 0; t < T_STEPS; ++t) {
    // h-part MFMAs: 2 independent chains of 8
    f32x4 acc0 = accX, acc1 = {0.f,0.f,0.f,0.f};
    #pragma unroll
    for (int kk = 0; kk < 8; ++kk) {
      bf16x8 a = *(const bf16x8*)(A_s + arow * 776 + kk * 32 + kg);
      bf16x8 b = *(const bf16x8*)(Whh_s + rl * 520 + kk * 32 + kg);
      acc0 = __builtin_amdgcn_mfma_f32_16x16x32_bf16(a, b, acc0, 0, 0, 0);
    }
    #pragma unroll
    for (int kk = 8; kk < 16; ++kk) {
      bf16x8 a = *(const bf16x8*)(A_s + arow * 776 + kk * 32 + kg);
      bf16x8 b = *(const bf16x8*)(Whh_s + rl * 520 + kk * 32 + kg);
      acc1 = __builtin_amdgcn_mfma_f32_16x16x32_bf16(a, b, acc1, 0, 0, 0);
    }
    #pragma unroll
    for (int r = 0; r < 4; ++r) {
      int m = (lane >> 4) * 4 + r;             // C/D: row=(lane>>4)*4+reg, col=lane&15
      gl[m * 64 + wave * 16 + (lane & 15)] = acc0[r] + acc1[r];
    }
    __syncthreads();                           // S1: gates visible

    // update (tid<128): gates -> c,h; h store; per-wave vmcnt drain; arrive tree
    float hv = 0.f;
    if (tid < 128) {
      float gi = gl[ub * 64 +      jl] + biasr[0];
      float gf = gl[ub * 64 + 16 + jl] + biasr[1];
      float gg = gl[ub * 64 + 32 + jl] + biasr[2];
      float go = gl[ub * 64 + 48 + jl] + biasr[3];
      float cv = sigm(gf) * c_reg + sigm(gi) * tanh_f(gg);
      c_reg = cv;
      hv = sigm(go) * tanh_f(cv);
      if (t + 1 < T_STEPS) {
        unsigned short* hd = hring + (size_t)((t + 1) & (NBUF - 1)) * (GB * HDIM);
        hd[ub * HDIM + jt * 16 + jl] = f2bf(hv);
        asm volatile("s_waitcnt vmcnt(0)" ::: "memory");   // this wave's h half at L2
        if (lane == 0) {
          // level-1 arrive (8 lines x 8 arrivals/step)
          unsigned v = __hip_atomic_fetch_add(&arr[aline * 32], 1u,
                                              __ATOMIC_RELAXED, __HIP_MEMORY_SCOPE_WORKGROUP);
          if (v == 8u * (unsigned)(t + 1) - 1u) {
            // line leader -> level-2 (8 leaders/step)
            unsigned w = __hip_atomic_fetch_add(&arr[8 * 32], 1u,
                                                __ATOMIC_RELAXED, __HIP_MEMORY_SCOPE_WORKGROUP);
            if (w == 8u * (unsigned)(t + 1) - 1u) {
              // step master: broadcast GO to 32 private mailboxes (fire-and-forget)
              #pragma unroll
              for (int r = 0; r < GWG; ++r)
                __hip_atomic_fetch_add(&arr[(9 + r) * 32], 1u,
                                       __ATOMIC_RELAXED, __HIP_MEMORY_SCOPE_WORKGROUP);
            }
          }
        }
      }
      out[((size_t)t * 64 + g * GB + ub) * 512 + jt * 16 + jl] = sigm(hv);
    }

    if (t + 1 < T_STEPS) {
      // overlap: x(t+1) projection while group finishes (2 chains of 4)
      {
        f32x4 xa = {0.f,0.f,0.f,0.f}, xb2 = {0.f,0.f,0.f,0.f};
        #pragma unroll
        for (int kx = 0; kx < 4; ++kx) {
          bf16x8 a = *(const bf16x8*)(A_s + arow * 776 + 512 + kx * 32 + kg);
          bf16x8 b = *(const bf16x8*)(Wih_s + rl * 264 + kx * 32 + kg);
          xa = __builtin_amdgcn_mfma_f32_16x16x32_bf16(a, b, xa, 0, 0, 0);
        }
        #pragma unroll
        for (int kx = 4; kx < 8; ++kx) {
          bf16x8 a = *(const bf16x8*)(A_s + arow * 776 + 512 + kx * 32 + kg);
          bf16x8 b = *(const bf16x8*)(Wih_s + rl * 264 + kx * 32 + kg);
          xb2 = __builtin_amdgcn_mfma_f32_16x16x32_bf16(a, b, xb2, 0, 0, 0);
        }
        #pragma unroll
        for (int r = 0; r < 4; ++r) accX[r] = xa[r] + xb2[r];
      }
      // poll private GO mailbox (tid 255, wave3 — reaches here earliest).
      // RMW-only (fresh by construction); provably live -> no escape cap.
      if (tid == 255) {
        const unsigned target = (unsigned)(t + 1);
        for (;;) {
          unsigned v = __hip_atomic_fetch_or(&arr[(9 + rank) * 32], 0x80000000u,
                                             __ATOMIC_RELAXED, __HIP_MEMORY_SCOPE_WORKGROUP);
          if ((v & 0x7FFFFFFFu) >= target) break;
        }
      }
      __syncthreads();                         // S3: h(t+1) ready group-wide
      // stage h(t+1) from ring (fresh ring addresses -> plain loads safe) + x(t+2)
      {
        const unsigned short* hs = hring + (size_t)((t + 1) & (NBUF - 1)) * (GB * HDIM)
                                 + sm * HDIM + sc * 16;
        bf16x8 h0 = *(const bf16x8*)(hs);
        bf16x8 h1 = *(const bf16x8*)(hs + 8);
        *(bf16x8*)(A_s + sm * 776 + sc * 16)     = h0;
        *(bf16x8*)(A_s + sm * 776 + sc * 16 + 8) = h1;
        if (t + 2 < T_STEPS) stage_x(x, A_s, g, sm, sc, t + 2);
      }
      __syncthreads();                         // S4: A_s consistent for next iter
    }
  }
}

extern "C" void kernel_launch(void* const* d_in, const int* in_sizes, int n_in,
                              void* d_out, int out_size, void* d_ws, size_t ws_size,
                              hipStream_t stream) {
  const float* x    = (const float*)d_in[0];
  const float* W_ih = (const float*)d_in[1];
  const float* W_hh = (const float*)d_in[2];
  const float* b_ih = (const float*)d_in[3];
  const float* b_hh = (const float*)d_in[4];
  float* out = (float*)d_out;
  unsigned char* ws = (unsigned char*)d_ws;

  hipLaunchKernelGGL(k_init, dim3(8),    dim3(256), 0, stream, ws);
  hipLaunchKernelGGL(k_pack, dim3(1024), dim3(256), 0, stream, W_ih, W_hh, b_ih, b_hh, ws);
  hipLaunchKernelGGL(k_lstm, dim3(512),  dim3(256), 0, stream, ws, x, out);
}

// Round 9
// 2848.997 us; speedup vs baseline: 4.6290x; 1.3002x over previous
//
#include <hip/hip_runtime.h>
#include <stdint.h>

#define T_STEPS 1024
#define BATCH   64
#define DIN     256
#define HDIM    512
#define G4      2048
#define NGRP    8        // groups = XCDs
#define GWG     32       // WGs per group
#define GB      8        // batches per group
#define NBUF    16       // h ring depth (defeats L1 reuse; WGs stay within 1 step)

// ---- workspace layout (bytes) ----
#define OFF_XCNT  0                            // 8 ints: per-XCD rank counters
#define OFF_ARR   1024                         // [8 groups][2 lines x 128B]
#define OFF_BIAS  8192                         // 2048 f32 (b_ih + b_hh)
#define OFF_WHH   16384                        // 2048*512 bf16 (2 MB)
#define OFF_WIH   (OFF_WHH + G4*HDIM*2)        // 2048*256 bf16 (1 MB)
#define OFF_H     (OFF_WIH + G4*DIN*2)         // [NGRP][NBUF][8][512] bf16 = 1 MB

typedef __attribute__((ext_vector_type(8))) short bf16x8;
typedef __attribute__((ext_vector_type(4))) float f32x4;

__device__ __forceinline__ unsigned short f2bf(float f) {
  union { float f; unsigned u; } v; v.f = f;
  unsigned r = v.u + 0x7FFF + ((v.u >> 16) & 1);
  return (unsigned short)(r >> 16);
}
__device__ __forceinline__ float sigm(float x)   { return 1.0f / (1.0f + __expf(-x)); }
__device__ __forceinline__ float tanh_f(float x) { return 2.0f / (1.0f + __expf(-2.0f * x)) - 1.0f; }

__global__ void k_init(unsigned char* ws) {
  int tid = blockIdx.x * blockDim.x + threadIdx.x;
  unsigned* w32 = (unsigned*)ws;
  for (int i = tid; i < 8192 / 4; i += gridDim.x * blockDim.x) w32[i] = 0;
}

__global__ void k_pack(const float* __restrict__ W_ih, const float* __restrict__ W_hh,
                       const float* __restrict__ b_ih, const float* __restrict__ b_hh,
                       unsigned char* ws) {
  unsigned short* whh = (unsigned short*)(ws + OFF_WHH);
  unsigned short* wih = (unsigned short*)(ws + OFF_WIH);
  float* bias = (float*)(ws + OFF_BIAS);
  int tid = blockIdx.x * blockDim.x + threadIdx.x;
  int np = gridDim.x * blockDim.x;
  for (int i = tid; i < G4 * HDIM; i += np) whh[i] = f2bf(W_hh[i]);
  for (int i = tid; i < G4 * DIN;  i += np) wih[i] = f2bf(W_ih[i]);
  for (int i = tid; i < G4;        i += np) bias[i] = b_ih[i] + b_hh[i];
}

// stage x[t] for this group's 8 batches into A_s x-region (bf16), direct from fp32 input
__device__ __forceinline__ void stage_x(const float* __restrict__ x, unsigned short* A_s,
                                        int g, int m, int c, int tstep) {
  const float* xb = x + ((size_t)(g * GB + m) * 1024 + tstep) * 256 + c * 8;
  float4 f0 = *(const float4*)(xb);
  float4 f1 = *(const float4*)(xb + 4);
  union { bf16x8 v; unsigned short s[8]; } u;
  u.s[0] = f2bf(f0.x); u.s[1] = f2bf(f0.y); u.s[2] = f2bf(f0.z); u.s[3] = f2bf(f0.w);
  u.s[4] = f2bf(f1.x); u.s[5] = f2bf(f1.y); u.s[6] = f2bf(f1.z); u.s[7] = f2bf(f1.w);
  *(bf16x8*)(A_s + m * 776 + 512 + c * 8) = u.v;
}

// 512 WGs x 256 thr launched; 32 participants per XCD (group = physical XCD).
// WG: 8 batches x 64 gate cols (4 gates x 16 j), K=768.
// Weights live in REGISTERS (96 VGPR/wave, loaded once). Waves split the K dim
// (6 kk each, all 4 gate-tiles); partial gates summed via LDS glp[4].
// Sync: RMW-only, 2 lines, per-wave arrivals, single poller (r5+r8 lessons).
__global__ __launch_bounds__(256, 1) void k_lstm(unsigned char* ws,
                                                 const float* __restrict__ x,
                                                 float* __restrict__ out) {
  __shared__ __attribute__((aligned(16))) unsigned short A_s[16 * 776];   // [16][512h|256x|8pad]
  __shared__ __attribute__((aligned(16))) float glp[4 * 16 * 64];         // per-wave gate partials
  __shared__ int s_rank;

  const int tid = threadIdx.x;

  unsigned xcc;
  asm("s_getreg_b32 %0, hwreg(HW_REG_XCC_ID)" : "=s"(xcc));
  xcc &= 7;
  unsigned* xcnt = (unsigned*)(ws + OFF_XCNT);
  if (tid == 0)
    s_rank = (int)__hip_atomic_fetch_add(&xcnt[xcc], 1u, __ATOMIC_RELAXED, __HIP_MEMORY_SCOPE_AGENT);
  __syncthreads();
  const int rank = s_rank;
  if (rank >= GWG) return;                    // non-participant exits, frees CU

  const int g  = (int)xcc;
  const int jt = rank;                        // j-tile 0..31 (16 j each)

  const unsigned short* whh_g = (const unsigned short*)(ws + OFF_WHH);
  const unsigned short* wih_g = (const unsigned short*)(ws + OFF_WIH);
  const float*          bias_g = (const float*)(ws + OFF_BIAS);
  unsigned short*       hring = (unsigned short*)(ws + OFF_H) + (size_t)g * (NBUF * GB * HDIM);
  unsigned*             arr   = (unsigned*)(ws + OFF_ARR + g * 256);   // 2 lines, 32 dw apart

  const int lane = tid & 63, wave = tid >> 6;
  const int arow = lane & 15;
  const int kg   = (lane >> 4) * 8;            // k sub-offset within 32-k step
  const int sm   = tid >> 5, sc = tid & 31;    // staging mapping: 8 rows x 32 thr

  // --- B fragments in registers: bq[u*4+nt], u=0..3 h-part (kk=wave*4+u),
  //     u=4..5 x-part (xk=wave*2+(u-4)). Compile-time indices only (rule #20).
  bf16x8 bq[24];
  {
    #pragma unroll
    for (int u = 0; u < 6; ++u)
      #pragma unroll
      for (int nt = 0; nt < 4; ++nt) {
        int grow = nt * 512 + jt * 16 + (lane & 15);   // gate col (B-frag: col=lane&15)
        const unsigned short* src;
        if (u < 4) src = whh_g + (size_t)grow * 512 + (wave * 4 + u) * 32 + kg;
        else       src = wih_g + (size_t)grow * 256 + (wave * 2 + (u - 4)) * 32 + kg;
        bq[u * 4 + nt] = *(const bf16x8*)src;
      }
  }

  // --- zero A_s (h(0)=0; pad rows 8..15 stay zero forever) ---
  {
    unsigned* a32 = (unsigned*)A_s;
    for (int i = tid; i < 16 * 776 / 2; i += 256) a32[i] = 0;
  }

  float biasr[4];
  float c_reg = 0.f;
  const int ub = tid >> 4, jl = tid & 15;     // updater mapping (tid<128)
  if (tid < 128) {
    #pragma unroll
    for (int gt = 0; gt < 4; ++gt)
      biasr[gt] = bias_g[gt * 512 + jt * 16 + jl];
  }

  __syncthreads();

  // --- preamble: stage x(0); accX partial(0); stage x(1) ---
  stage_x(x, A_s, g, sm, sc, 0);
  __syncthreads();
  f32x4 accX[4];
  {
    #pragma unroll
    for (int nt = 0; nt < 4; ++nt) accX[nt] = (f32x4){0.f, 0.f, 0.f, 0.f};
    #pragma unroll
    for (int j = 0; j < 2; ++j) {
      int xk = wave * 2 + j;
      bf16x8 a = *(const bf16x8*)(A_s + arow * 776 + 512 + xk * 32 + kg);
      #pragma unroll
      for (int nt = 0; nt < 4; ++nt)
        accX[nt] = __builtin_amdgcn_mfma_f32_16x16x32_bf16(a, bq[(4 + j) * 4 + nt], accX[nt], 0, 0, 0);
    }
  }
  __syncthreads();
  stage_x(x, A_s, g, sm, sc, 1);
  __syncthreads();

  // --- main loop. Top of iter t: A_s-h = h(t), A_s-x = x(t+1), accX = x-partial(t). ---
  for (int t = 0; t < T_STEPS; ++t) {
    // h-part: this wave's 4 kk-steps, all 4 gate-tiles
    f32x4 acc[4];
    #pragma unroll
    for (int nt = 0; nt < 4; ++nt) acc[nt] = accX[nt];
    #pragma unroll
    for (int u = 0; u < 4; ++u) {
      int kk = wave * 4 + u;
      bf16x8 a = *(const bf16x8*)(A_s + arow * 776 + kk * 32 + kg);
      #pragma unroll
      for (int nt = 0; nt < 4; ++nt)
        acc[nt] = __builtin_amdgcn_mfma_f32_16x16x32_bf16(a, bq[u * 4 + nt], acc[nt], 0, 0, 0);
    }
    // write this wave's partial gates
    #pragma unroll
    for (int nt = 0; nt < 4; ++nt)
      #pragma unroll
      for (int r = 0; r < 4; ++r) {
        int m = (lane >> 4) * 4 + r;           // C/D: row=(lane>>4)*4+reg, col=lane&15
        glp[wave * 1024 + m * 64 + nt * 16 + (lane & 15)] = acc[nt][r];
      }
    __syncthreads();                           // S1: partials visible

    // update (tid<128): sum 4 partials, gates -> c,h; store; per-wave drain+arrive
    float hv = 0.f;
    if (tid < 128) {
      float gs[4];
      #pragma unroll
      for (int gt = 0; gt < 4; ++gt)
        gs[gt] = glp[ub * 64 + gt * 16 + jl]
               + glp[1024 + ub * 64 + gt * 16 + jl]
               + glp[2048 + ub * 64 + gt * 16 + jl]
               + glp[3072 + ub * 64 + gt * 16 + jl] + biasr[gt];
      float cv = sigm(gs[1]) * c_reg + sigm(gs[0]) * tanh_f(gs[2]);
      c_reg = cv;
      hv = sigm(gs[3]) * tanh_f(cv);
      if (t + 1 < T_STEPS) {
        unsigned short* hd = hring + (size_t)((t + 1) & (NBUF - 1)) * (GB * HDIM);
        hd[ub * HDIM + jt * 16 + jl] = f2bf(hv);
        asm volatile("s_waitcnt vmcnt(0)" ::: "memory");   // this wave's h half at L2
        if (lane == 0)                                      // per-wave arrival, own line
          __hip_atomic_fetch_add(&arr[wave * 32], 1u,
                                 __ATOMIC_RELAXED, __HIP_MEMORY_SCOPE_WORKGROUP);
      }
      out[((size_t)t * 64 + g * GB + ub) * 512 + jt * 16 + jl] = sigm(hv);
    }

    if (t + 1 < T_STEPS) {
      // overlap: this wave's x-partial for t+1 (waves 2,3 reach here immediately)
      #pragma unroll
      for (int nt = 0; nt < 4; ++nt) accX[nt] = (f32x4){0.f, 0.f, 0.f, 0.f};
      #pragma unroll
      for (int j = 0; j < 2; ++j) {
        int xk = wave * 2 + j;
        bf16x8 a = *(const bf16x8*)(A_s + arow * 776 + 512 + xk * 32 + kg);
        #pragma unroll
        for (int nt = 0; nt < 4; ++nt)
          accX[nt] = __builtin_amdgcn_mfma_f32_16x16x32_bf16(a, bq[(4 + j) * 4 + nt], accX[nt], 0, 0, 0);
      }
      // single poller, 2 lines, direct RMW poll (non-identity; fresh at L2; no caps)
      if (tid == 192) {
        const unsigned target = 32u * (unsigned)(t + 1);
        for (;;) {
          unsigned v0 = __hip_atomic_fetch_or(&arr[0], 0x80000000u,
                                              __ATOMIC_RELAXED, __HIP_MEMORY_SCOPE_WORKGROUP);
          unsigned v1 = __hip_atomic_fetch_or(&arr[32], 0x80000000u,
                                              __ATOMIC_RELAXED, __HIP_MEMORY_SCOPE_WORKGROUP);
          if ((v0 & 0x7FFFFFFFu) >= target && (v1 & 0x7FFFFFFFu) >= target) break;
        }
      }
      __syncthreads();                         // S3: h(t+1) ready group-wide
      // stage h(t+1) from ring (fresh ring addresses -> plain loads safe) + x(t+2)
      {
        const unsigned short* hs = hring + (size_t)((t + 1) & (NBUF - 1)) * (GB * HDIM)
                                 + sm * HDIM + sc * 16;
        bf16x8 h0 = *(const bf16x8*)(hs);
        bf16x8 h1 = *(const bf16x8*)(hs + 8);
        *(bf16x8*)(A_s + sm * 776 + sc * 16)     = h0;
        *(bf16x8*)(A_s + sm * 776 + sc * 16 + 8) = h1;
        if (t + 2 < T_STEPS) stage_x(x, A_s, g, sm, sc, t + 2);
      }
      __syncthreads();                         // S4: A_s consistent for next iter
    }
  }
}

extern "C" void kernel_launch(void* const* d_in, const int* in_sizes, int n_in,
                              void* d_out, int out_size, void* d_ws, size_t ws_size,
                              hipStream_t stream) {
  const float* x    = (const float*)d_in[0];
  const float* W_ih = (const float*)d_in[1];
  const float* W_hh = (const float*)d_in[2];
  const float* b_ih = (const float*)d_in[3];
  const float* b_hh = (const float*)d_in[4];
  float* out = (float*)d_out;
  unsigned char* ws = (unsigned char*)d_ws;

  hipLaunchKernelGGL(k_init, dim3(8),    dim3(256), 0, stream, ws);
  hipLaunchKernelGGL(k_pack, dim3(1024), dim3(256), 0, stream, W_ih, W_hh, b_ih, b_hh, ws);
  hipLaunchKernelGGL(k_lstm, dim3(512),  dim3(256), 0, stream, ws, x, out);
}